// Round 1
// baseline (6259.261 us; speedup 1.0000x reference)
//
#include <hip/hip_runtime.h>
#include <math.h>

#define EPS 1e-5f

// Model dims: B=64, T=512, CIN=4, E=256, H=8, dh=32, S=513, L=4, NC=2.
// Workspace use: ~194 MiB (see offsets in kernel_launch).

__device__ __forceinline__ float gelu_f(float x) {
  return 0.5f * x * (1.0f + erff(x * 0.70710678118654752440f));
}
__device__ __forceinline__ float sigmoid_f(float x) {
  return 1.0f / (1.0f + __expf(-x));
}

// ---------------- prep: fold conv bias + eval-BN into scale/shift ----------------
__global__ void prep_kernel(const float* __restrict__ c1b, const float* __restrict__ g1,
                            const float* __restrict__ b1, const float* __restrict__ c2b,
                            const float* __restrict__ g2, const float* __restrict__ b2,
                            float* __restrict__ eff) {
  const int t = threadIdx.x;
  const float bninv = rsqrtf(1.0f + EPS);
  const float e1g = bninv * g1[t];
  eff[t]       = e1g;
  eff[256 + t] = c1b[t] * e1g + b1[t];
  const float e2g = bninv * g2[t];
  eff[512 + t] = e2g;
  eff[768 + t] = c2b[t] * e2g + b2[t];
}

// w2k[k][e][ci] = conv2_w[e][ci][k]
__global__ void repack_w2_kernel(const float* __restrict__ w2, float* __restrict__ w2k) {
  const int idx = blockIdx.x * 256 + threadIdx.x;   // 3*256*256 total
  const int k = idx >> 16;
  const int rem = idx & 65535;                       // e*256+ci
  w2k[idx] = w2[rem * 3 + k];
}

// zero padding rows of x1p [B][T+2][E]
__global__ void zeropad_kernel(float* __restrict__ x1p) {
  const int b = blockIdx.x, tid = threadIdx.x;
  x1p[((long)b * 514) * 256 + tid] = 0.f;
  x1p[((long)b * 514 + 513) * 256 + tid] = 0.f;
}

// ---------------- conv1 + BN + GELU -> x1p [B][T+2][E] (rows 1..T) ----------------
__global__ __launch_bounds__(256) void conv1_kernel(const float* __restrict__ in,
                                                    const float* __restrict__ w1,
                                                    const float* __restrict__ eff,
                                                    float* __restrict__ x1p) {
  const int b = blockIdx.y, t0 = blockIdx.x * 64;
  const int tid = threadIdx.x;
  __shared__ float4 Ls[66];
  __shared__ float Wl[3072];
  if (tid < 66) {
    const int t = t0 - 1 + tid;
    float4 v = make_float4(0.f, 0.f, 0.f, 0.f);
    if (t >= 0 && t < 512) v = *(const float4*)(in + ((long)b * 512 + t) * 4);
    Ls[tid] = v;
  }
#pragma unroll
  for (int i = 0; i < 12; ++i) Wl[i * 256 + tid] = w1[i * 256 + tid];
  __syncthreads();
  float w[12];
#pragma unroll
  for (int i = 0; i < 12; ++i) w[i] = Wl[tid * 12 + i];  // [c*3+k]
  const float eg = eff[tid], eb = eff[256 + tid];
  float* outp = x1p + ((long)b * 514 + t0 + 1) * 256 + tid;
  for (int tl = 0; tl < 64; ++tl) {
    const float4 i0 = Ls[tl], i1 = Ls[tl + 1], i2 = Ls[tl + 2];
    float s = i0.x * w[0] + i1.x * w[1] + i2.x * w[2]
            + i0.y * w[3] + i1.y * w[4] + i2.y * w[5]
            + i0.z * w[6] + i1.z * w[7] + i2.z * w[8]
            + i0.w * w[9] + i1.w * w[10] + i2.w * w[11];
    outp[(long)tl * 256] = gelu_f(s * eg + eb);
  }
}

// ---------------- generic GEMM: C[M,N] = epi(A@W^T) ----------------
// Epilogue order: if ACC add old C; if SCALE *= scale[n]; += bias[n] (nullable); if GELU.
// Row remap (for shifted conv2 reads): arow = (m/groupT)*strideA + m%groupT + rowOff.
// Requires: M,N multiples of 64; K multiple of 16; groupT multiple of 64 (or >= M).
template <bool ACC, bool GELU_, bool SCALE>
__global__ __launch_bounds__(256) void gemm_kernel(const float* __restrict__ A,
                                                   const float* __restrict__ W,
                                                   const float* __restrict__ bias,
                                                   const float* __restrict__ scale,
                                                   float* __restrict__ C, int M, int N, int K,
                                                   int groupT, int strideA, int rowOff) {
  __shared__ float As[16][68];
  __shared__ float Bs[16][68];
  const int m0 = blockIdx.x * 64, n0 = blockIdx.y * 64;
  const int g = m0 / groupT, r0 = m0 - g * groupT;
  const float* Ab = A + (long)(g * strideA + r0 + rowOff) * K;
  const float* Wb = W + (long)n0 * K;
  const int tid = threadIdx.x;
  const int lr = tid >> 2;
  const int lk = (tid & 3) << 2;
  const int tr = (tid >> 4) << 2;
  const int tc = (tid & 15) << 2;
  float acc[4][4] = {{0.f}};
  for (int k0 = 0; k0 < K; k0 += 16) {
    const float4 a4 = *(const float4*)(Ab + (long)lr * K + k0 + lk);
    const float4 b4 = *(const float4*)(Wb + (long)lr * K + k0 + lk);
    __syncthreads();
    As[lk + 0][lr] = a4.x; As[lk + 1][lr] = a4.y; As[lk + 2][lr] = a4.z; As[lk + 3][lr] = a4.w;
    Bs[lk + 0][lr] = b4.x; Bs[lk + 1][lr] = b4.y; Bs[lk + 2][lr] = b4.z; Bs[lk + 3][lr] = b4.w;
    __syncthreads();
#pragma unroll
    for (int kk = 0; kk < 16; ++kk) {
      const float4 av = *(const float4*)&As[kk][tr];
      const float4 bv = *(const float4*)&Bs[kk][tc];
      acc[0][0] += av.x * bv.x; acc[0][1] += av.x * bv.y; acc[0][2] += av.x * bv.z; acc[0][3] += av.x * bv.w;
      acc[1][0] += av.y * bv.x; acc[1][1] += av.y * bv.y; acc[1][2] += av.y * bv.z; acc[1][3] += av.y * bv.w;
      acc[2][0] += av.z * bv.x; acc[2][1] += av.z * bv.y; acc[2][2] += av.z * bv.z; acc[2][3] += av.z * bv.w;
      acc[3][0] += av.w * bv.x; acc[3][1] += av.w * bv.y; acc[3][2] += av.w * bv.z; acc[3][3] += av.w * bv.w;
    }
  }
  float4 bb = make_float4(0.f, 0.f, 0.f, 0.f);
  if (bias) bb = *(const float4*)(bias + n0 + tc);
  float4 sv = make_float4(1.f, 1.f, 1.f, 1.f);
  if (SCALE) sv = *(const float4*)(scale + n0 + tc);
#pragma unroll
  for (int i = 0; i < 4; ++i) {
    float* cp = C + (long)(m0 + tr + i) * N + n0 + tc;
    float4 v = make_float4(acc[i][0], acc[i][1], acc[i][2], acc[i][3]);
    if (ACC) {
      const float4 c4 = *(const float4*)cp;
      v.x += c4.x; v.y += c4.y; v.z += c4.z; v.w += c4.w;
    }
    if (SCALE) { v.x *= sv.x; v.y *= sv.y; v.z *= sv.z; v.w *= sv.w; }
    v.x += bb.x; v.y += bb.y; v.z += bb.z; v.w += bb.w;
    if (GELU_) { v.x = gelu_f(v.x); v.y = gelu_f(v.y); v.z = gelu_f(v.z); v.w = gelu_f(v.w); }
    *(float4*)cp = v;
  }
}

// ---------------- SE gates ----------------
__global__ __launch_bounds__(256) void ca_mean_kernel(const float* __restrict__ x2,
                                                      float* __restrict__ ca) {
  const int b = blockIdx.x, tid = threadIdx.x;
  float s = 0.f;
  for (int t = 0; t < 512; ++t) s += x2[((long)(b * 512 + t)) * 256 + tid];
  ca[b * 256 + tid] = s * (1.0f / 512.0f);
}

__global__ __launch_bounds__(256) void gate1_kernel(const float* __restrict__ ca,
    const float* __restrict__ w1, const float* __restrict__ b1,
    const float* __restrict__ lng, const float* __restrict__ lnb,
    const float* __restrict__ w2, const float* __restrict__ b2, float* __restrict__ ge) {
  const int b = blockIdx.x, tid = threadIdx.x;
  __shared__ float caL[256];
  __shared__ float zL[32];
  caL[tid] = ca[b * 256 + tid];
  __syncthreads();
  if (tid < 32) {
    float s = b1[tid];
    for (int e = 0; e < 256; ++e) s += caL[e] * w1[tid * 256 + e];
    float mean = s;
    for (int msk = 1; msk < 32; msk <<= 1) mean += __shfl_xor(mean, msk);
    mean *= (1.0f / 32.0f);
    const float d = s - mean;
    float v = d * d;
    for (int msk = 1; msk < 32; msk <<= 1) v += __shfl_xor(v, msk);
    v *= (1.0f / 32.0f);
    zL[tid] = gelu_f(d * rsqrtf(v + EPS) * lng[tid] + lnb[tid]);
  }
  __syncthreads();
  float a = b2[tid];
#pragma unroll
  for (int j = 0; j < 32; ++j) a += zL[j] * w2[tid * 32 + j];
  ge[b * 256 + tid] = sigmoid_f(a);
}

// ta[b,t] = mean_e(x2[b,t,e]*ge[b,e])
__global__ __launch_bounds__(256) void ta_mean_kernel(const float* __restrict__ x2,
                                                      const float* __restrict__ ge,
                                                      float* __restrict__ ta) {
  const int b = blockIdx.x, tid = threadIdx.x;
  const int w = tid >> 6, lane = tid & 63;
  const float4 g4 = *(const float4*)(ge + b * 256 + lane * 4);
  for (int t = w; t < 512; t += 4) {
    const float4 x4 = *(const float4*)(x2 + ((long)(b * 512 + t)) * 256 + lane * 4);
    float s = x4.x * g4.x + x4.y * g4.y + x4.z * g4.z + x4.w * g4.w;
#pragma unroll
    for (int msk = 32; msk; msk >>= 1) s += __shfl_xor(s, msk);
    if (lane == 0) ta[b * 512 + t] = s * (1.0f / 256.0f);
  }
}

__global__ __launch_bounds__(256) void gate2_kernel(const float* __restrict__ ta,
    const float* __restrict__ w1, const float* __restrict__ b1,
    const float* __restrict__ lng, const float* __restrict__ lnb,
    const float* __restrict__ w2, const float* __restrict__ b2, float* __restrict__ gt) {
  const int b = blockIdx.x, tid = threadIdx.x;
  __shared__ float taL[512];
  __shared__ float zL[64];
  taL[tid] = ta[b * 512 + tid];
  taL[256 + tid] = ta[b * 512 + 256 + tid];
  __syncthreads();
  if (tid < 64) {
    float s = b1[tid];
    for (int t = 0; t < 512; ++t) s += taL[t] * w1[tid * 512 + t];
    float mean = s;
    for (int msk = 1; msk < 64; msk <<= 1) mean += __shfl_xor(mean, msk);
    mean *= (1.0f / 64.0f);
    const float d = s - mean;
    float v = d * d;
    for (int msk = 1; msk < 64; msk <<= 1) v += __shfl_xor(v, msk);
    v *= (1.0f / 64.0f);
    zL[tid] = gelu_f(d * rsqrtf(v + EPS) * lng[tid] + lnb[tid]);
  }
  __syncthreads();
#pragma unroll
  for (int r = 0; r < 2; ++r) {
    const int t = tid + r * 256;
    float a = b2[t];
    for (int j = 0; j < 64; ++j) a += zL[j] * w2[t * 64 + j];
    gt[b * 512 + t] = sigmoid_f(a);
  }
}

// x_seq[b,0,:]=cls; x_seq[b,1+t,e] = x2*ge*gt + pos(t,e)
__global__ __launch_bounds__(256) void xseq_kernel(const float* __restrict__ x2,
    const float* __restrict__ ge, const float* __restrict__ gt,
    const float* __restrict__ cls, float* __restrict__ x) {
  const int srow = blockIdx.x, b = blockIdx.y, e = threadIdx.x;
  float* outp = x + ((long)(b * 513 + srow)) * 256 + e;
  if (srow == 0) { *outp = cls[e]; return; }
  const int t = srow - 1;
  float val = x2[((long)(b * 512 + t)) * 256 + e] * ge[b * 256 + e] * gt[b * 512 + t];
  const float freq = __expf((float)(e & ~1) * (-0.03597789207803197f));  // -ln(10000)/256
  const float ang = (float)t * freq;
  val += (e & 1) ? cosf(ang) : sinf(ang);
  *outp = val;
}

// ---------------- LayerNorm (rows x D), D in {256,1024}, optional GELU ----------------
template <bool GELU_>
__global__ __launch_bounds__(256) void ln_kernel(const float* __restrict__ in,
                                                 const float* __restrict__ g,
                                                 const float* __restrict__ bta,
                                                 float* __restrict__ out, int D, int ostride) {
  const int row = blockIdx.x, tid = threadIdx.x;
  __shared__ float red[8];
  const float* x = in + (long)row * D;
  const int nv = D >> 8;
  float xv[4];
  float s = 0.f;
  for (int i = 0; i < nv; ++i) { xv[i] = x[tid + (i << 8)]; s += xv[i]; }
#pragma unroll
  for (int msk = 32; msk; msk >>= 1) s += __shfl_xor(s, msk);
  if ((tid & 63) == 0) red[tid >> 6] = s;
  __syncthreads();
  s = red[0] + red[1] + red[2] + red[3];
  const float mean = s / (float)D;
  float vs = 0.f;
  for (int i = 0; i < nv; ++i) { const float d = xv[i] - mean; vs += d * d; }
#pragma unroll
  for (int msk = 32; msk; msk >>= 1) vs += __shfl_xor(vs, msk);
  if ((tid & 63) == 0) red[4 + (tid >> 6)] = vs;
  __syncthreads();
  vs = red[4] + red[5] + red[6] + red[7];
  const float inv = rsqrtf(vs / (float)D + EPS);
  for (int i = 0; i < nv; ++i) {
    const int col = tid + (i << 8);
    float y = (xv[i] - mean) * inv * g[col] + bta[col];
    if (GELU_) y = gelu_f(y);
    out[(long)row * ostride + col] = y;
  }
}

// ---------------- flash-style attention: dh=32, online softmax ----------------
// grid(17 qtiles, H=8, B=64), 256 threads; thread=(row=tid/8, d0=(tid&7)*4).
__global__ __launch_bounds__(256) void attn_kernel(const float* __restrict__ qkv,
                                                   float* __restrict__ o) {
  const int qt = blockIdx.x, h = blockIdx.y, b = blockIdx.z;
  const int tid = threadIdx.x;
  const int row = tid >> 3, sub = tid & 7, d0 = sub << 2;
  __shared__ float Qt[32][33];
  __shared__ float Ktt[32][36];  // transposed: [d][kk]
  __shared__ float Vt[32][32];
  __shared__ float Pt[32][33];
  const int q0 = qt * 32;
  const int qs = q0 + row;
  float4 qv = make_float4(0.f, 0.f, 0.f, 0.f);
  if (qs < 513) qv = *(const float4*)(qkv + ((long)(b * 513 + qs)) * 768 + h * 32 + d0);
  Qt[row][d0 + 0] = qv.x; Qt[row][d0 + 1] = qv.y; Qt[row][d0 + 2] = qv.z; Qt[row][d0 + 3] = qv.w;
  float m = -1e30f, l = 0.f;
  float4 oa = make_float4(0.f, 0.f, 0.f, 0.f);
  const float sf = 0.17677669529663687f;  // 1/sqrt(32)
  for (int k0 = 0; k0 < 513; k0 += 32) {
    __syncthreads();
    {
      const int ks = k0 + row;
      float4 kv = make_float4(0.f, 0.f, 0.f, 0.f), vv = make_float4(0.f, 0.f, 0.f, 0.f);
      if (ks < 513) {
        const float* kb = qkv + ((long)(b * 513 + ks)) * 768 + 256 + h * 32 + d0;
        kv = *(const float4*)kb;
        vv = *(const float4*)(kb + 256);
      }
      Ktt[d0 + 0][row] = kv.x; Ktt[d0 + 1][row] = kv.y; Ktt[d0 + 2][row] = kv.z; Ktt[d0 + 3][row] = kv.w;
      *(float4*)&Vt[row][d0] = vv;
    }
    __syncthreads();
    float s0 = 0.f, s1 = 0.f, s2 = 0.f, s3 = 0.f;
    const int kk0 = sub << 2;
#pragma unroll
    for (int d = 0; d < 32; ++d) {
      const float q = Qt[row][d];
      const float4 k4 = *(const float4*)&Ktt[d][kk0];
      s0 += q * k4.x; s1 += q * k4.y; s2 += q * k4.z; s3 += q * k4.w;
    }
    s0 *= sf; s1 *= sf; s2 *= sf; s3 *= sf;
    const int kg = k0 + kk0;
    if (kg + 0 >= 513) s0 = -1e30f;
    if (kg + 1 >= 513) s1 = -1e30f;
    if (kg + 2 >= 513) s2 = -1e30f;
    if (kg + 3 >= 513) s3 = -1e30f;
    float tm = fmaxf(fmaxf(s0, s1), fmaxf(s2, s3));
    tm = fmaxf(tm, __shfl_xor(tm, 1));
    tm = fmaxf(tm, __shfl_xor(tm, 2));
    tm = fmaxf(tm, __shfl_xor(tm, 4));
    const float mn = fmaxf(m, tm);
    const float al = __expf(m - mn);
    const float p0 = __expf(s0 - mn), p1 = __expf(s1 - mn), p2 = __expf(s2 - mn), p3 = __expf(s3 - mn);
    float ps = p0 + p1 + p2 + p3;
    ps += __shfl_xor(ps, 1); ps += __shfl_xor(ps, 2); ps += __shfl_xor(ps, 4);
    l = l * al + ps;
    m = mn;
    oa.x *= al; oa.y *= al; oa.z *= al; oa.w *= al;
    Pt[row][kk0 + 0] = p0; Pt[row][kk0 + 1] = p1; Pt[row][kk0 + 2] = p2; Pt[row][kk0 + 3] = p3;
    __syncthreads();
#pragma unroll
    for (int kk = 0; kk < 32; ++kk) {
      const float p = Pt[row][kk];
      const float4 v4 = *(const float4*)&Vt[kk][d0];
      oa.x += p * v4.x; oa.y += p * v4.y; oa.z += p * v4.z; oa.w += p * v4.w;
    }
  }
  if (qs < 513) {
    const float inv = 1.0f / l;
    *(float4*)(o + ((long)(b * 513 + qs)) * 256 + h * 32 + d0) =
        make_float4(oa.x * inv, oa.y * inv, oa.z * inv, oa.w * inv);
  }
}

// ---------------- small tail kernels ----------------
__global__ void gather_cls_kernel(const float* __restrict__ x, float* __restrict__ gr) {
  gr[blockIdx.x * 256 + threadIdx.x] = x[((long)blockIdx.x * 513) * 256 + threadIdx.x];
}

__global__ void final_kernel(const float* __restrict__ c2, const float* __restrict__ w,
                             const float* __restrict__ bias, float* __restrict__ out) {
  const int tid = threadIdx.x;  // 128 threads: (b, n)
  const int b = tid >> 1, n = tid & 1;
  float s = bias[n];
  for (int j = 0; j < 256; ++j) s += c2[b * 256 + j] * w[n * 256 + j];
  out[b * 2 + n] = s;
}

extern "C" void kernel_launch(void* const* d_in, const int* in_sizes, int n_in, void* d_out,
                              int out_size, void* d_ws, size_t ws_size, hipStream_t stream) {
  const float* acc_data = (const float*)d_in[0];
  const float* conv1_w = (const float*)d_in[1];
  const float* conv1_b = (const float*)d_in[2];
  const float* bn1_g = (const float*)d_in[3];
  const float* bn1_b = (const float*)d_in[4];
  const float* conv2_w = (const float*)d_in[5];
  const float* conv2_b = (const float*)d_in[6];
  const float* bn2_g = (const float*)d_in[7];
  const float* bn2_b = (const float*)d_in[8];
  const float* sa_w1 = (const float*)d_in[9];
  const float* sa_b1 = (const float*)d_in[10];
  const float* sa_ln_g = (const float*)d_in[11];
  const float* sa_ln_b = (const float*)d_in[12];
  const float* sa_w2 = (const float*)d_in[13];
  const float* sa_b2 = (const float*)d_in[14];
  const float* ca_w1 = (const float*)d_in[15];
  const float* ca_b1 = (const float*)d_in[16];
  const float* ca_ln_g = (const float*)d_in[17];
  const float* ca_ln_b = (const float*)d_in[18];
  const float* ca_w2 = (const float*)d_in[19];
  const float* ca_b2 = (const float*)d_in[20];
  const float* cls_token = (const float*)d_in[21];
  const float* n1_g = (const float*)d_in[22];
  const float* n1_b = (const float*)d_in[23];
  const float* attn_in_w = (const float*)d_in[24];
  const float* attn_in_b = (const float*)d_in[25];
  const float* attn_out_w = (const float*)d_in[26];
  const float* attn_out_b = (const float*)d_in[27];
  const float* n2_g = (const float*)d_in[28];
  const float* n2_b = (const float*)d_in[29];
  const float* mlp_w1 = (const float*)d_in[30];
  const float* mlp_b1 = (const float*)d_in[31];
  const float* mlp_w2 = (const float*)d_in[32];
  const float* mlp_b2 = (const float*)d_in[33];
  const float* fus_w = (const float*)d_in[34];
  const float* fus_b = (const float*)d_in[35];
  const float* fus_ln_g = (const float*)d_in[36];
  const float* fus_ln_b = (const float*)d_in[37];
  const float* clf_ln_g = (const float*)d_in[38];
  const float* clf_ln_b = (const float*)d_in[39];
  const float* clf_w1 = (const float*)d_in[40];
  const float* clf_b1 = (const float*)d_in[41];
  const float* clf_w2 = (const float*)d_in[42];
  const float* clf_b2 = (const float*)d_in[43];

  float* ws = (float*)d_ws;
  // workspace layout (floats); total ~50.9M floats (~194 MiB)
  float* BIG = ws;                   // 33,619,968 : x1p (conv), then qkv [B,S,768], then h [B,S,1024]
  float* XN = BIG + 33619968L;       //  8,404,992 : x2 [B,T,E], then LN-out / attn-o [B,S,E]
  float* X = XN + 8404992L;          //  8,404,992 : x_seq [B,S,E]
  float* W2K = X + 8404992L;         //    196,608 : repacked conv2 weights [3][E][E]
  float* EFF = W2K + 196608L;        //      1,024 : folded conv scale/shift
  float* CA = EFF + 1024;            //     16,384
  float* GE = CA + 16384;            //     16,384
  float* TA = GE + 16384;            //     32,768
  float* GT = TA + 32768;            //     32,768
  float* FEATS = GT + 32768;         //     65,536
  float* YT = FEATS + 65536;         //     16,384
  float* CLN = YT + 16384;           //     65,536
  float* C2 = CLN + 65536;           //     16,384
  float* GR = C2 + 16384;            //     16,384

  const int GBIG = 1 << 30;

  prep_kernel<<<1, 256, 0, stream>>>(conv1_b, bn1_g, bn1_b, conv2_b, bn2_g, bn2_b, EFF);
  repack_w2_kernel<<<768, 256, 0, stream>>>(conv2_w, W2K);
  zeropad_kernel<<<64, 256, 0, stream>>>(BIG);
  conv1_kernel<<<dim3(8, 64), 256, 0, stream>>>(acc_data, conv1_w, EFF, BIG);
  // conv2 = 3 shifted accumulate GEMMs over x1p; epilogue folds BN+GELU.
  gemm_kernel<false, false, false><<<dim3(512, 4), 256, 0, stream>>>(
      BIG, W2K, nullptr, nullptr, XN, 32768, 256, 256, 512, 514, 0);
  gemm_kernel<true, false, false><<<dim3(512, 4), 256, 0, stream>>>(
      BIG, W2K + 65536, nullptr, nullptr, XN, 32768, 256, 256, 512, 514, 1);
  gemm_kernel<true, true, true><<<dim3(512, 4), 256, 0, stream>>>(
      BIG, W2K + 131072, EFF + 768, EFF + 512, XN, 32768, 256, 256, 512, 514, 2);
  ca_mean_kernel<<<64, 256, 0, stream>>>(XN, CA);
  gate1_kernel<<<64, 256, 0, stream>>>(CA, sa_w1, sa_b1, sa_ln_g, sa_ln_b, sa_w2, sa_b2, GE);
  ta_mean_kernel<<<64, 256, 0, stream>>>(XN, GE, TA);
  gate2_kernel<<<64, 256, 0, stream>>>(TA, ca_w1, ca_b1, ca_ln_g, ca_ln_b, ca_w2, ca_b2, GT);
  xseq_kernel<<<dim3(513, 64), 256, 0, stream>>>(XN, GE, GT, cls_token, X);

  for (int i = 0; i < 4; ++i) {
    ln_kernel<false><<<32832, 256, 0, stream>>>(X, n1_g + i * 256, n1_b + i * 256, XN, 256, 256);
    gemm_kernel<false, false, false><<<dim3(513, 12), 256, 0, stream>>>(
        XN, attn_in_w + (long)i * 768 * 256, attn_in_b + i * 768, nullptr, BIG,
        32832, 768, 256, GBIG, 0, 0);
    attn_kernel<<<dim3(17, 8, 64), 256, 0, stream>>>(BIG, XN);
    gemm_kernel<true, false, false><<<dim3(513, 4), 256, 0, stream>>>(
        XN, attn_out_w + (long)i * 65536, attn_out_b + i * 256, nullptr, X,
        32832, 256, 256, GBIG, 0, 0);
    ln_kernel<false><<<32832, 256, 0, stream>>>(X, n2_g + i * 256, n2_b + i * 256, XN, 256, 256);
    gemm_kernel<false, true, false><<<dim3(513, 16), 256, 0, stream>>>(
        XN, mlp_w1 + (long)i * 262144, mlp_b1 + i * 1024, nullptr, BIG,
        32832, 1024, 256, GBIG, 0, 0);
    gemm_kernel<true, false, false><<<dim3(513, 4), 256, 0, stream>>>(
        BIG, mlp_w2 + (long)i * 262144, mlp_b2 + i * 256, nullptr, X,
        32832, 256, 1024, GBIG, 0, 0);
    gather_cls_kernel<<<64, 256, 0, stream>>>(X, GR);
    gemm_kernel<false, false, false><<<dim3(1, 4), 256, 0, stream>>>(
        GR, fus_w + (long)i * 65536, fus_b + i * 256, nullptr, YT, 64, 256, 256, GBIG, 0, 0);
    ln_kernel<true><<<64, 256, 0, stream>>>(YT, fus_ln_g + i * 256, fus_ln_b + i * 256,
                                            FEATS + i * 256, 256, 1024);
  }
  ln_kernel<false><<<64, 256, 0, stream>>>(FEATS, clf_ln_g, clf_ln_b, CLN, 1024, 1024);
  gemm_kernel<false, true, false><<<dim3(1, 4), 256, 0, stream>>>(
      CLN, clf_w1, clf_b1, nullptr, C2, 64, 256, 1024, GBIG, 0, 0);
  final_kernel<<<1, 128, 0, stream>>>(C2, clf_w2, clf_b2, (float*)d_out);
}

// Round 2
// 3314.907 us; speedup vs baseline: 1.8882x; 1.8882x over previous
//
#include <hip/hip_runtime.h>
#include <math.h>

#define EPS 1e-5f

// Model dims: B=64, T=512, CIN=4, E=256, H=8, dh=32, S=513, L=4, NC=2.

typedef __attribute__((ext_vector_type(8))) short short8;
typedef __attribute__((ext_vector_type(4))) float f32x4;

__device__ __forceinline__ float gelu_f(float x) {
  return 0.5f * x * (1.0f + erff(x * 0.70710678118654752440f));
}
__device__ __forceinline__ float sigmoid_f(float x) {
  return 1.0f / (1.0f + __expf(-x));
}
__device__ __forceinline__ unsigned short f2bf(float f) {
  unsigned int u = __float_as_uint(f);
  u = (u + 0x7FFFu + ((u >> 16) & 1u)) >> 16;
  return (unsigned short)u;
}
__device__ __forceinline__ float bf2f(unsigned short s) {
  return __uint_as_float(((unsigned int)s) << 16);
}
__device__ __forceinline__ void gl_lds16(const unsigned short* g, unsigned short* l) {
  __builtin_amdgcn_global_load_lds(
      (const __attribute__((address_space(1))) void*)g,
      (__attribute__((address_space(3))) void*)l, 16, 0, 0);
}

// ---------------- prep: fold conv bias + eval-BN into scale/shift ----------------
__global__ void prep_kernel(const float* __restrict__ c1b, const float* __restrict__ g1,
                            const float* __restrict__ b1, const float* __restrict__ c2b,
                            const float* __restrict__ g2, const float* __restrict__ b2,
                            float* __restrict__ eff) {
  const int t = threadIdx.x;
  const float bninv = rsqrtf(1.0f + EPS);
  const float e1g = bninv * g1[t];
  eff[t]       = e1g;
  eff[256 + t] = c1b[t] * e1g + b1[t];
  const float e2g = bninv * g2[t];
  eff[512 + t] = e2g;
  eff[768 + t] = c2b[t] * e2g + b2[t];
}

// generic f32 -> bf16 convert
__global__ void f2bf_kernel(const float* __restrict__ src, unsigned short* __restrict__ dst,
                            int n) {
  const int i = blockIdx.x * 256 + threadIdx.x;
  if (i < n) dst[i] = f2bf(src[i]);
}

// w2e[e][s*256+ci] = conv2_w[e][ci][s]  (bf16), so conv2 == one K=768 GEMM
__global__ void repack_w2_kernel(const float* __restrict__ w2, unsigned short* __restrict__ w2e) {
  const int idx = blockIdx.x * 256 + threadIdx.x;  // 256*768
  const int e = idx / 768, rem = idx % 768;
  const int s = rem >> 8, ci = rem & 255;
  w2e[idx] = f2bf(w2[e * 768 + ci * 3 + s]);
}

// zero padding rows of x1p [B][T+2][E] (bf16)
__global__ void zeropad_kernel(unsigned short* __restrict__ x1p) {
  const int b = blockIdx.x, tid = threadIdx.x;
  x1p[((long)b * 514) * 256 + tid] = 0;
  x1p[((long)b * 514 + 513) * 256 + tid] = 0;
}

// ---------------- conv1 + BN + GELU -> x1p [B][T+2][E] bf16 (rows 1..T) ----------------
__global__ __launch_bounds__(256) void conv1_kernel(const float* __restrict__ in,
                                                    const float* __restrict__ w1,
                                                    const float* __restrict__ eff,
                                                    unsigned short* __restrict__ x1p) {
  const int b = blockIdx.y, t0 = blockIdx.x * 64;
  const int tid = threadIdx.x;
  __shared__ float4 Ls[66];
  __shared__ float Wl[3072];
  if (tid < 66) {
    const int t = t0 - 1 + tid;
    float4 v = make_float4(0.f, 0.f, 0.f, 0.f);
    if (t >= 0 && t < 512) v = *(const float4*)(in + ((long)b * 512 + t) * 4);
    Ls[tid] = v;
  }
#pragma unroll
  for (int i = 0; i < 12; ++i) Wl[i * 256 + tid] = w1[i * 256 + tid];
  __syncthreads();
  float w[12];
#pragma unroll
  for (int i = 0; i < 12; ++i) w[i] = Wl[tid * 12 + i];  // [c*3+k]
  const float eg = eff[tid], eb = eff[256 + tid];
  unsigned short* outp = x1p + ((long)b * 514 + t0 + 1) * 256 + tid;
  for (int tl = 0; tl < 64; ++tl) {
    const float4 i0 = Ls[tl], i1 = Ls[tl + 1], i2 = Ls[tl + 2];
    float s = i0.x * w[0] + i1.x * w[1] + i2.x * w[2]
            + i0.y * w[3] + i1.y * w[4] + i2.y * w[5]
            + i0.z * w[6] + i1.z * w[7] + i2.z * w[8]
            + i0.w * w[9] + i1.w * w[10] + i2.w * w[11];
    outp[(long)tl * 256] = f2bf(gelu_f(s * eg + eb));
  }
}

// ---------------- bf16 MFMA GEMM: C[M,N] = epi(A@W^T) ----------------
// A bf16 [M x K] with row stride lda (and optional group remap for conv2),
// W bf16 [N x K], fp32 accumulate via v_mfma_f32_16x16x32_bf16.
// 128x128 tile, BK=32, 256 threads (4 waves 2x2, each 64x64 = 4x4 MFMA tiles).
// Epilogue: if ACC add fp32 C; if SCALE *= scale[n]; += bias[n]; if GELU_; out f32 or bf16.
template <bool OUTBF, bool ACC, bool GELU_, bool SCALE>
__global__ __launch_bounds__(256) void bgemm_kernel(
    const unsigned short* __restrict__ A, const unsigned short* __restrict__ W,
    const float* __restrict__ bias, const float* __restrict__ scale,
    float* __restrict__ Cf, unsigned short* __restrict__ Cb,
    int M, int N, int K, int lda, int groupT, int strideA) {
  __shared__ __align__(16) unsigned short As[4096];  // [128][32]
  __shared__ __align__(16) unsigned short Bs[4096];  // [128][32]
  const int tid = threadIdx.x;
  const int lane = tid & 63;
  const int m0 = blockIdx.x << 7, n0 = blockIdx.y << 7;
  const int g = m0 / groupT;
  const long abase = (long)(g * strideA + (m0 - g * groupT)) * lda;
  // staging: 512 16B-chunks per tile; chunk c -> row c/4, k-chunk c%4; 2 per thread.
  const int c0 = tid, c1 = tid + 256;
  const int r0c = c0 >> 2, k0c = (c0 & 3) << 3;
  const int r1c = c1 >> 2, k1c = (c1 & 3) << 3;
  const int mEdge = M - m0 - 1;
  const int r0a = r0c <= mEdge ? r0c : mEdge;
  const int r1a = r1c <= mEdge ? r1c : mEdge;
  const unsigned short* a0p = A + abase + (long)r0a * lda + k0c;
  const unsigned short* a1p = A + abase + (long)r1a * lda + k1c;
  const unsigned short* b0p = W + (long)(n0 + r0c) * K + k0c;
  const unsigned short* b1p = W + (long)(n0 + r1c) * K + k1c;
  unsigned short* As0 = &As[c0 * 8];
  unsigned short* As1 = &As[c1 * 8];
  unsigned short* Bs0 = &Bs[c0 * 8];
  unsigned short* Bs1 = &Bs[c1 * 8];
  const int fr = lane & 15, kg = lane >> 4;
  const unsigned short* arp = &As[(((tid >> 7) << 6) + fr) * 32 + kg * 8];
  const unsigned short* brp = &Bs[((((tid >> 6) & 1) << 6) + fr) * 32 + kg * 8];
  f32x4 acc[4][4];
#pragma unroll
  for (int i = 0; i < 4; ++i)
#pragma unroll
    for (int j = 0; j < 4; ++j) acc[i][j] = f32x4{0.f, 0.f, 0.f, 0.f};
  for (int k0 = 0; k0 < K; k0 += 32) {
    gl_lds16(a0p + k0, As0);
    gl_lds16(a1p + k0, As1);
    gl_lds16(b0p + k0, Bs0);
    gl_lds16(b1p + k0, Bs1);
    __syncthreads();
    short8 af[4], bfr[4];
#pragma unroll
    for (int i = 0; i < 4; ++i) af[i] = *(const short8*)(arp + i * 512);
#pragma unroll
    for (int j = 0; j < 4; ++j) bfr[j] = *(const short8*)(brp + j * 512);
#pragma unroll
    for (int i = 0; i < 4; ++i)
#pragma unroll
      for (int j = 0; j < 4; ++j)
        acc[i][j] = __builtin_amdgcn_mfma_f32_16x16x32_bf16(af[i], bfr[j], acc[i][j], 0, 0, 0);
    __syncthreads();
  }
  // epilogue: C/D layout col=lane&15, row=(lane>>4)*4+reg
  const int colb = n0 + (((tid >> 6) & 1) << 6) + fr;
  float bj[4], sj[4];
#pragma unroll
  for (int j = 0; j < 4; ++j) {
    bj[j] = bias ? bias[colb + j * 16] : 0.f;
    sj[j] = SCALE ? scale[colb + j * 16] : 1.f;
  }
  const int rowb = m0 + ((tid >> 7) << 6) + kg * 4;
#pragma unroll
  for (int i = 0; i < 4; ++i) {
#pragma unroll
    for (int r = 0; r < 4; ++r) {
      const int row = rowb + i * 16 + r;
      if (row < M) {
#pragma unroll
        for (int j = 0; j < 4; ++j) {
          const long off = (long)row * N + colb + j * 16;
          float v = acc[i][j][r];
          if (ACC) v += Cf[off];
          if (SCALE) v *= sj[j];
          v += bj[j];
          if (GELU_) v = gelu_f(v);
          if (OUTBF) Cb[off] = f2bf(v);
          else Cf[off] = v;
        }
      }
    }
  }
}

// ---------------- fp32 GEMM (tiny tail mats only): C[M,N] = epi(A@W^T) ----------------
template <bool ACC, bool GELU_, bool SCALE>
__global__ __launch_bounds__(256) void gemm_kernel(const float* __restrict__ A,
                                                   const float* __restrict__ W,
                                                   const float* __restrict__ bias,
                                                   const float* __restrict__ scale,
                                                   float* __restrict__ C, int M, int N, int K,
                                                   int groupT, int strideA, int rowOff) {
  __shared__ float As[16][68];
  __shared__ float Bs[16][68];
  const int m0 = blockIdx.x * 64, n0 = blockIdx.y * 64;
  const int g = m0 / groupT, r0 = m0 - g * groupT;
  const float* Ab = A + (long)(g * strideA + r0 + rowOff) * K;
  const float* Wb = W + (long)n0 * K;
  const int tid = threadIdx.x;
  const int lr = tid >> 2;
  const int lk = (tid & 3) << 2;
  const int tr = (tid >> 4) << 2;
  const int tc = (tid & 15) << 2;
  float acc[4][4] = {{0.f}};
  for (int k0 = 0; k0 < K; k0 += 16) {
    const float4 a4 = *(const float4*)(Ab + (long)lr * K + k0 + lk);
    const float4 b4 = *(const float4*)(Wb + (long)lr * K + k0 + lk);
    __syncthreads();
    As[lk + 0][lr] = a4.x; As[lk + 1][lr] = a4.y; As[lk + 2][lr] = a4.z; As[lk + 3][lr] = a4.w;
    Bs[lk + 0][lr] = b4.x; Bs[lk + 1][lr] = b4.y; Bs[lk + 2][lr] = b4.z; Bs[lk + 3][lr] = b4.w;
    __syncthreads();
#pragma unroll
    for (int kk = 0; kk < 16; ++kk) {
      const float4 av = *(const float4*)&As[kk][tr];
      const float4 bv = *(const float4*)&Bs[kk][tc];
      acc[0][0] += av.x * bv.x; acc[0][1] += av.x * bv.y; acc[0][2] += av.x * bv.z; acc[0][3] += av.x * bv.w;
      acc[1][0] += av.y * bv.x; acc[1][1] += av.y * bv.y; acc[1][2] += av.y * bv.z; acc[1][3] += av.y * bv.w;
      acc[2][0] += av.z * bv.x; acc[2][1] += av.z * bv.y; acc[2][2] += av.z * bv.z; acc[2][3] += av.z * bv.w;
      acc[3][0] += av.w * bv.x; acc[3][1] += av.w * bv.y; acc[3][2] += av.w * bv.z; acc[3][3] += av.w * bv.w;
    }
  }
  float4 bb = make_float4(0.f, 0.f, 0.f, 0.f);
  if (bias) bb = *(const float4*)(bias + n0 + tc);
  float4 sv = make_float4(1.f, 1.f, 1.f, 1.f);
  if (SCALE) sv = *(const float4*)(scale + n0 + tc);
#pragma unroll
  for (int i = 0; i < 4; ++i) {
    float* cp = C + (long)(m0 + tr + i) * N + n0 + tc;
    float4 v = make_float4(acc[i][0], acc[i][1], acc[i][2], acc[i][3]);
    if (ACC) {
      const float4 c4 = *(const float4*)cp;
      v.x += c4.x; v.y += c4.y; v.z += c4.z; v.w += c4.w;
    }
    if (SCALE) { v.x *= sv.x; v.y *= sv.y; v.z *= sv.z; v.w *= sv.w; }
    v.x += bb.x; v.y += bb.y; v.z += bb.z; v.w += bb.w;
    if (GELU_) { v.x = gelu_f(v.x); v.y = gelu_f(v.y); v.z = gelu_f(v.z); v.w = gelu_f(v.w); }
    *(float4*)cp = v;
  }
}

// ---------------- SE gates (fp32, x2 fp32) ----------------
__global__ __launch_bounds__(256) void ca_mean_kernel(const float* __restrict__ x2,
                                                      float* __restrict__ ca) {
  const int b = blockIdx.x, tid = threadIdx.x;
  float s = 0.f;
  for (int t = 0; t < 512; ++t) s += x2[((long)(b * 512 + t)) * 256 + tid];
  ca[b * 256 + tid] = s * (1.0f / 512.0f);
}

__global__ __launch_bounds__(256) void gate1_kernel(const float* __restrict__ ca,
    const float* __restrict__ w1, const float* __restrict__ b1,
    const float* __restrict__ lng, const float* __restrict__ lnb,
    const float* __restrict__ w2, const float* __restrict__ b2, float* __restrict__ ge) {
  const int b = blockIdx.x, tid = threadIdx.x;
  __shared__ float caL[256];
  __shared__ float zL[32];
  caL[tid] = ca[b * 256 + tid];
  __syncthreads();
  if (tid < 32) {
    float s = b1[tid];
    for (int e = 0; e < 256; ++e) s += caL[e] * w1[tid * 256 + e];
    float mean = s;
    for (int msk = 1; msk < 32; msk <<= 1) mean += __shfl_xor(mean, msk);
    mean *= (1.0f / 32.0f);
    const float d = s - mean;
    float v = d * d;
    for (int msk = 1; msk < 32; msk <<= 1) v += __shfl_xor(v, msk);
    v *= (1.0f / 32.0f);
    zL[tid] = gelu_f(d * rsqrtf(v + EPS) * lng[tid] + lnb[tid]);
  }
  __syncthreads();
  float a = b2[tid];
#pragma unroll
  for (int j = 0; j < 32; ++j) a += zL[j] * w2[tid * 32 + j];
  ge[b * 256 + tid] = sigmoid_f(a);
}

__global__ __launch_bounds__(256) void ta_mean_kernel(const float* __restrict__ x2,
                                                      const float* __restrict__ ge,
                                                      float* __restrict__ ta) {
  const int b = blockIdx.x, tid = threadIdx.x;
  const int w = tid >> 6, lane = tid & 63;
  const float4 g4 = *(const float4*)(ge + b * 256 + lane * 4);
  for (int t = w; t < 512; t += 4) {
    const float4 x4 = *(const float4*)(x2 + ((long)(b * 512 + t)) * 256 + lane * 4);
    float s = x4.x * g4.x + x4.y * g4.y + x4.z * g4.z + x4.w * g4.w;
#pragma unroll
    for (int msk = 32; msk; msk >>= 1) s += __shfl_xor(s, msk);
    if (lane == 0) ta[b * 512 + t] = s * (1.0f / 256.0f);
  }
}

__global__ __launch_bounds__(256) void gate2_kernel(const float* __restrict__ ta,
    const float* __restrict__ w1, const float* __restrict__ b1,
    const float* __restrict__ lng, const float* __restrict__ lnb,
    const float* __restrict__ w2, const float* __restrict__ b2, float* __restrict__ gt) {
  const int b = blockIdx.x, tid = threadIdx.x;
  __shared__ float taL[512];
  __shared__ float zL[64];
  taL[tid] = ta[b * 512 + tid];
  taL[256 + tid] = ta[b * 512 + 256 + tid];
  __syncthreads();
  if (tid < 64) {
    float s = b1[tid];
    for (int t = 0; t < 512; ++t) s += taL[t] * w1[tid * 512 + t];
    float mean = s;
    for (int msk = 1; msk < 64; msk <<= 1) mean += __shfl_xor(mean, msk);
    mean *= (1.0f / 64.0f);
    const float d = s - mean;
    float v = d * d;
    for (int msk = 1; msk < 64; msk <<= 1) v += __shfl_xor(v, msk);
    v *= (1.0f / 64.0f);
    zL[tid] = gelu_f(d * rsqrtf(v + EPS) * lng[tid] + lnb[tid]);
  }
  __syncthreads();
#pragma unroll
  for (int r = 0; r < 2; ++r) {
    const int t = tid + r * 256;
    float a = b2[t];
    for (int j = 0; j < 64; ++j) a += zL[j] * w2[t * 64 + j];
    gt[b * 512 + t] = sigmoid_f(a);
  }
}

// x_seq[b,0,:]=cls; x_seq[b,1+t,e] = x2*ge*gt + pos(t,e)  (fp32 residual stream)
__global__ __launch_bounds__(256) void xseq_kernel(const float* __restrict__ x2,
    const float* __restrict__ ge, const float* __restrict__ gt,
    const float* __restrict__ cls, float* __restrict__ x) {
  const int srow = blockIdx.x, b = blockIdx.y, e = threadIdx.x;
  float* outp = x + ((long)(b * 513 + srow)) * 256 + e;
  if (srow == 0) { *outp = cls[e]; return; }
  const int t = srow - 1;
  float val = x2[((long)(b * 512 + t)) * 256 + e] * ge[b * 256 + e] * gt[b * 512 + t];
  const float freq = __expf((float)(e & ~1) * (-0.03597789207803197f));  // -ln(10000)/256
  const float ang = (float)t * freq;
  val += (e & 1) ? cosf(ang) : sinf(ang);
  *outp = val;
}

// ---------------- LayerNorm (rows x D), fp32 in, fp32 or bf16 out ----------------
template <bool GELU_, bool OUTBF>
__global__ __launch_bounds__(256) void ln_kernel(const float* __restrict__ in,
                                                 const float* __restrict__ g,
                                                 const float* __restrict__ bta,
                                                 void* __restrict__ out, int D, int ostride) {
  const int row = blockIdx.x, tid = threadIdx.x;
  __shared__ float red[8];
  const float* x = in + (long)row * D;
  const int nv = D >> 8;
  float xv[4];
  float s = 0.f;
  for (int i = 0; i < nv; ++i) { xv[i] = x[tid + (i << 8)]; s += xv[i]; }
#pragma unroll
  for (int msk = 32; msk; msk >>= 1) s += __shfl_xor(s, msk);
  if ((tid & 63) == 0) red[tid >> 6] = s;
  __syncthreads();
  s = red[0] + red[1] + red[2] + red[3];
  const float mean = s / (float)D;
  float vs = 0.f;
  for (int i = 0; i < nv; ++i) { const float d = xv[i] - mean; vs += d * d; }
#pragma unroll
  for (int msk = 32; msk; msk >>= 1) vs += __shfl_xor(vs, msk);
  if ((tid & 63) == 0) red[4 + (tid >> 6)] = vs;
  __syncthreads();
  vs = red[4] + red[5] + red[6] + red[7];
  const float inv = rsqrtf(vs / (float)D + EPS);
  for (int i = 0; i < nv; ++i) {
    const int col = tid + (i << 8);
    float y = (xv[i] - mean) * inv * g[col] + bta[col];
    if (GELU_) y = gelu_f(y);
    if (OUTBF) ((unsigned short*)out)[(long)row * ostride + col] = f2bf(y);
    else ((float*)out)[(long)row * ostride + col] = y;
  }
}

// ---------------- flash-style attention: fp32 compute, bf16 I/O ----------------
__global__ __launch_bounds__(256) void attn_kernel(const unsigned short* __restrict__ qkv,
                                                   unsigned short* __restrict__ o) {
  const int qt = blockIdx.x, h = blockIdx.y, b = blockIdx.z;
  const int tid = threadIdx.x;
  const int row = tid >> 3, sub = tid & 7, d0 = sub << 2;
  __shared__ float Qt[32][33];
  __shared__ float Ktt[32][36];
  __shared__ float Vt[32][32];
  __shared__ float Pt[32][33];
  const int q0 = qt * 32;
  const int qs = q0 + row;
  float4 qv = make_float4(0.f, 0.f, 0.f, 0.f);
  if (qs < 513) {
    const ushort4 q4 = *(const ushort4*)(qkv + ((long)(b * 513 + qs)) * 768 + h * 32 + d0);
    qv = make_float4(bf2f(q4.x), bf2f(q4.y), bf2f(q4.z), bf2f(q4.w));
  }
  Qt[row][d0 + 0] = qv.x; Qt[row][d0 + 1] = qv.y; Qt[row][d0 + 2] = qv.z; Qt[row][d0 + 3] = qv.w;
  float m = -1e30f, l = 0.f;
  float4 oa = make_float4(0.f, 0.f, 0.f, 0.f);
  const float sf = 0.17677669529663687f;  // 1/sqrt(32)
  for (int k0 = 0; k0 < 513; k0 += 32) {
    __syncthreads();
    {
      const int ks = k0 + row;
      float4 kv = make_float4(0.f, 0.f, 0.f, 0.f), vv = make_float4(0.f, 0.f, 0.f, 0.f);
      if (ks < 513) {
        const unsigned short* kb = qkv + ((long)(b * 513 + ks)) * 768 + 256 + h * 32 + d0;
        const ushort4 k4 = *(const ushort4*)kb;
        const ushort4 v4 = *(const ushort4*)(kb + 256);
        kv = make_float4(bf2f(k4.x), bf2f(k4.y), bf2f(k4.z), bf2f(k4.w));
        vv = make_float4(bf2f(v4.x), bf2f(v4.y), bf2f(v4.z), bf2f(v4.w));
      }
      Ktt[d0 + 0][row] = kv.x; Ktt[d0 + 1][row] = kv.y; Ktt[d0 + 2][row] = kv.z; Ktt[d0 + 3][row] = kv.w;
      *(float4*)&Vt[row][d0] = vv;
    }
    __syncthreads();
    float s0 = 0.f, s1 = 0.f, s2 = 0.f, s3 = 0.f;
    const int kk0 = sub << 2;
#pragma unroll
    for (int d = 0; d < 32; ++d) {
      const float q = Qt[row][d];
      const float4 k4 = *(const float4*)&Ktt[d][kk0];
      s0 += q * k4.x; s1 += q * k4.y; s2 += q * k4.z; s3 += q * k4.w;
    }
    s0 *= sf; s1 *= sf; s2 *= sf; s3 *= sf;
    const int kg = k0 + kk0;
    if (kg + 0 >= 513) s0 = -1e30f;
    if (kg + 1 >= 513) s1 = -1e30f;
    if (kg + 2 >= 513) s2 = -1e30f;
    if (kg + 3 >= 513) s3 = -1e30f;
    float tm = fmaxf(fmaxf(s0, s1), fmaxf(s2, s3));
    tm = fmaxf(tm, __shfl_xor(tm, 1));
    tm = fmaxf(tm, __shfl_xor(tm, 2));
    tm = fmaxf(tm, __shfl_xor(tm, 4));
    const float mn = fmaxf(m, tm);
    const float al = __expf(m - mn);
    const float p0 = __expf(s0 - mn), p1 = __expf(s1 - mn), p2 = __expf(s2 - mn), p3 = __expf(s3 - mn);
    float ps = p0 + p1 + p2 + p3;
    ps += __shfl_xor(ps, 1); ps += __shfl_xor(ps, 2); ps += __shfl_xor(ps, 4);
    l = l * al + ps;
    m = mn;
    oa.x *= al; oa.y *= al; oa.z *= al; oa.w *= al;
    Pt[row][kk0 + 0] = p0; Pt[row][kk0 + 1] = p1; Pt[row][kk0 + 2] = p2; Pt[row][kk0 + 3] = p3;
    __syncthreads();
#pragma unroll
    for (int kk = 0; kk < 32; ++kk) {
      const float p = Pt[row][kk];
      const float4 v4 = *(const float4*)&Vt[kk][d0];
      oa.x += p * v4.x; oa.y += p * v4.y; oa.z += p * v4.z; oa.w += p * v4.w;
    }
  }
  if (qs < 513) {
    const float inv = 1.0f / l;
    ushort4 r;
    r.x = f2bf(oa.x * inv); r.y = f2bf(oa.y * inv);
    r.z = f2bf(oa.z * inv); r.w = f2bf(oa.w * inv);
    *(ushort4*)(o + ((long)(b * 513 + qs)) * 256 + h * 32 + d0) = r;
  }
}

// ---------------- small tail kernels ----------------
__global__ void gather_cls_kernel(const float* __restrict__ x, float* __restrict__ gr) {
  gr[blockIdx.x * 256 + threadIdx.x] = x[((long)blockIdx.x * 513) * 256 + threadIdx.x];
}

__global__ void final_kernel(const float* __restrict__ c2, const float* __restrict__ w,
                             const float* __restrict__ bias, float* __restrict__ out) {
  const int tid = threadIdx.x;  // 128 threads: (b, n)
  const int b = tid >> 1, n = tid & 1;
  float s = bias[n];
  for (int j = 0; j < 256; ++j) s += c2[b * 256 + j] * w[n * 256 + j];
  out[b * 2 + n] = s;
}

extern "C" void kernel_launch(void* const* d_in, const int* in_sizes, int n_in, void* d_out,
                              int out_size, void* d_ws, size_t ws_size, hipStream_t stream) {
  const float* acc_data = (const float*)d_in[0];
  const float* conv1_w = (const float*)d_in[1];
  const float* conv1_b = (const float*)d_in[2];
  const float* bn1_g = (const float*)d_in[3];
  const float* bn1_b = (const float*)d_in[4];
  const float* conv2_w = (const float*)d_in[5];
  const float* conv2_b = (const float*)d_in[6];
  const float* bn2_g = (const float*)d_in[7];
  const float* bn2_b = (const float*)d_in[8];
  const float* sa_w1 = (const float*)d_in[9];
  const float* sa_b1 = (const float*)d_in[10];
  const float* sa_ln_g = (const float*)d_in[11];
  const float* sa_ln_b = (const float*)d_in[12];
  const float* sa_w2 = (const float*)d_in[13];
  const float* sa_b2 = (const float*)d_in[14];
  const float* ca_w1 = (const float*)d_in[15];
  const float* ca_b1 = (const float*)d_in[16];
  const float* ca_ln_g = (const float*)d_in[17];
  const float* ca_ln_b = (const float*)d_in[18];
  const float* ca_w2 = (const float*)d_in[19];
  const float* ca_b2 = (const float*)d_in[20];
  const float* cls_token = (const float*)d_in[21];
  const float* n1_g = (const float*)d_in[22];
  const float* n1_b = (const float*)d_in[23];
  const float* attn_in_w = (const float*)d_in[24];
  const float* attn_in_b = (const float*)d_in[25];
  const float* attn_out_w = (const float*)d_in[26];
  const float* attn_out_b = (const float*)d_in[27];
  const float* n2_g = (const float*)d_in[28];
  const float* n2_b = (const float*)d_in[29];
  const float* mlp_w1 = (const float*)d_in[30];
  const float* mlp_b1 = (const float*)d_in[31];
  const float* mlp_w2 = (const float*)d_in[32];
  const float* mlp_b2 = (const float*)d_in[33];
  const float* fus_w = (const float*)d_in[34];
  const float* fus_b = (const float*)d_in[35];
  const float* fus_ln_g = (const float*)d_in[36];
  const float* fus_ln_b = (const float*)d_in[37];
  const float* clf_ln_g = (const float*)d_in[38];
  const float* clf_ln_b = (const float*)d_in[39];
  const float* clf_w1 = (const float*)d_in[40];
  const float* clf_b1 = (const float*)d_in[41];
  const float* clf_w2 = (const float*)d_in[42];
  const float* clf_b2 = (const float*)d_in[43];

  // ---- workspace layout (bytes) ----
  char* p = (char*)d_ws;
  unsigned short* R1 = (unsigned short*)p;           // H bf16 [32832,1024] / x1p bf16 [64,514,256]
  p += 67239936L;
  char* R2 = p;                                      // x2 f32 [32768,256] then QKV bf16 [32832,768]
  p += 50429952L;
  float* X = (float*)p;       p += 33619968L;        // residual [32832,256] f32
  unsigned short* XN = (unsigned short*)p; p += 16809984L;  // LN out bf16
  unsigned short* O = (unsigned short*)p;  p += 16809984L;  // attn out bf16
  unsigned short* WQKV = (unsigned short*)p; p += 786432L * 2;
  unsigned short* WAO = (unsigned short*)p;  p += 262144L * 2;
  unsigned short* WM1 = (unsigned short*)p;  p += 1048576L * 2;
  unsigned short* WM2 = (unsigned short*)p;  p += 1048576L * 2;
  unsigned short* W2E = (unsigned short*)p;  p += 196608L * 2;
  float* EFF = (float*)p;    p += 1024L * 4;
  float* CA = (float*)p;     p += 16384L * 4;
  float* GE = (float*)p;     p += 16384L * 4;
  float* TA = (float*)p;     p += 32768L * 4;
  float* GT = (float*)p;     p += 32768L * 4;
  float* FEATS = (float*)p;  p += 65536L * 4;
  float* YT = (float*)p;     p += 16384L * 4;
  float* CLN = (float*)p;    p += 65536L * 4;
  float* C2 = (float*)p;     p += 16384L * 4;
  float* GR = (float*)p;     p += 16384L * 4;

  unsigned short* X1P = R1;
  float* X2 = (float*)R2;
  unsigned short* QKV = (unsigned short*)R2;
  unsigned short* Hb = R1;

  const int GBIG = 1 << 30;

  // weight prep
  prep_kernel<<<1, 256, 0, stream>>>(conv1_b, bn1_g, bn1_b, conv2_b, bn2_g, bn2_b, EFF);
  repack_w2_kernel<<<768, 256, 0, stream>>>(conv2_w, W2E);
  f2bf_kernel<<<3072, 256, 0, stream>>>(attn_in_w, WQKV, 786432);
  f2bf_kernel<<<1024, 256, 0, stream>>>(attn_out_w, WAO, 262144);
  f2bf_kernel<<<4096, 256, 0, stream>>>(mlp_w1, WM1, 1048576);
  f2bf_kernel<<<4096, 256, 0, stream>>>(mlp_w2, WM2, 1048576);

  // conv encoder
  zeropad_kernel<<<64, 256, 0, stream>>>(X1P);
  conv1_kernel<<<dim3(8, 64), 256, 0, stream>>>(acc_data, conv1_w, EFF, X1P);
  // conv2 as ONE K=768 GEMM over padded contiguous rows; BN+GELU epilogue -> x2 fp32
  bgemm_kernel<false, false, true, true><<<dim3(256, 2), 256, 0, stream>>>(
      X1P, W2E, EFF + 768, EFF + 512, X2, nullptr, 32768, 256, 768, 256, 512, 514);
  // SE gates + sequence build (fp32)
  ca_mean_kernel<<<64, 256, 0, stream>>>(X2, CA);
  gate1_kernel<<<64, 256, 0, stream>>>(CA, sa_w1, sa_b1, sa_ln_g, sa_ln_b, sa_w2, sa_b2, GE);
  ta_mean_kernel<<<64, 256, 0, stream>>>(X2, GE, TA);
  gate2_kernel<<<64, 256, 0, stream>>>(TA, ca_w1, ca_b1, ca_ln_g, ca_ln_b, ca_w2, ca_b2, GT);
  xseq_kernel<<<dim3(513, 64), 256, 0, stream>>>(X2, GE, GT, cls_token, X);

  for (int i = 0; i < 4; ++i) {
    ln_kernel<false, true><<<32832, 256, 0, stream>>>(X, n1_g + i * 256, n1_b + i * 256, XN, 256, 256);
    bgemm_kernel<true, false, false, false><<<dim3(257, 6), 256, 0, stream>>>(
        XN, WQKV + (long)i * 196608, attn_in_b + i * 768, nullptr, nullptr, QKV,
        32832, 768, 256, 256, GBIG, 0);
    attn_kernel<<<dim3(17, 8, 64), 256, 0, stream>>>(QKV, O);
    bgemm_kernel<false, true, false, false><<<dim3(257, 2), 256, 0, stream>>>(
        O, WAO + (long)i * 65536, attn_out_b + i * 256, nullptr, X, nullptr,
        32832, 256, 256, 256, GBIG, 0);
    ln_kernel<false, true><<<32832, 256, 0, stream>>>(X, n2_g + i * 256, n2_b + i * 256, XN, 256, 256);
    bgemm_kernel<true, false, true, false><<<dim3(257, 8), 256, 0, stream>>>(
        XN, WM1 + (long)i * 262144, mlp_b1 + i * 1024, nullptr, nullptr, Hb,
        32832, 1024, 256, 256, GBIG, 0);
    bgemm_kernel<false, true, false, false><<<dim3(257, 2), 256, 0, stream>>>(
        Hb, WM2 + (long)i * 262144, mlp_b2 + i * 256, nullptr, X, nullptr,
        32832, 256, 1024, 1024, GBIG, 0);
    gather_cls_kernel<<<64, 256, 0, stream>>>(X, GR);
    gemm_kernel<false, false, false><<<dim3(1, 4), 256, 0, stream>>>(
        GR, fus_w + (long)i * 65536, fus_b + i * 256, nullptr, YT, 64, 256, 256, GBIG, 0, 0);
    ln_kernel<true, false><<<64, 256, 0, stream>>>(YT, fus_ln_g + i * 256, fus_ln_b + i * 256,
                                                   FEATS + i * 256, 256, 1024);
  }
  ln_kernel<false, false><<<64, 256, 0, stream>>>(FEATS, clf_ln_g, clf_ln_b, CLN, 1024, 1024);
  gemm_kernel<false, true, false><<<dim3(1, 4), 256, 0, stream>>>(
      CLN, clf_w1, clf_b1, nullptr, C2, 64, 256, 1024, GBIG, 0, 0);
  final_kernel<<<1, 128, 0, stream>>>(C2, clf_w2, clf_b2, (float*)d_out);
}